// Round 5
// baseline (979.874 us; speedup 1.0000x reference)
//
#include <hip/hip_runtime.h>

#define N_PTS 65536
#define BN_EPS 1e-5f
#define NB  512           // grid blocks (2 per CU, co-resident by construction)
#define RPB 128           // rows per block

typedef __attribute__((ext_vector_type(8))) short bf16x8;
typedef __attribute__((ext_vector_type(4))) float f32x4;

static __device__ __forceinline__ unsigned short f2bf(float f) {
    unsigned u = __builtin_bit_cast(unsigned, f);
    u += 0x7fffu + ((u >> 16) & 1u);          // round-to-nearest-even
    return (unsigned short)(u >> 16);
}
static __device__ __forceinline__ float bf2f(unsigned short h) {
    unsigned u = ((unsigned)h) << 16;
    return __builtin_bit_cast(float, u);
}

// ---------------------------------------------------------------------------
// split 8 weight matrices into bf16 hi/lo; slot = kind*2 + d, 4096 elems each
__global__ __launch_bounds__(256) void wconv_kernel(
    const float* __restrict__ fc1, const float* __restrict__ la1,
    const float* __restrict__ la2, const float* __restrict__ fc3,
    unsigned short* __restrict__ hi, unsigned short* __restrict__ lo)
{
    int i = blockIdx.x * 256 + threadIdx.x;   // 0..32767
    const float* p = (i < 8192) ? fc1 : (i < 16384) ? la1
                   : (i < 24576) ? la2 : fc3;
    float w = p[i & 8191];
    unsigned short h = f2bf(w);
    hi[i] = h;
    lo[i] = f2bf(w - bf2f(h));
}

// ---------------------------------------------------------------------------
struct FParams {
    const float* feat; const int* ref;
    const unsigned short* Whi; const unsigned short* Wlo;
    const float* la_b1; const float* la_b2;
    const float* bn1_g; const float* bn1_b;
    const float* la_bn1g; const float* la_bn1b;
    const float* la_bn2g; const float* la_bn2b;
    const float* bn2_g; const float* bn2_b;
    const float* bn3_g; const float* bn3_b;
    unsigned* cnt;
    float* Sb;            // 10 slots * 512 floats (4 shadows * (sum64|ss64))
    unsigned* bar;        // [0]=count, [32]=generation
    float* y3;
    float* out;
};

// ---------------------------------------------------------------------------
// grid-wide sense-reversing barrier (manual; all NB blocks co-resident)
static __device__ __forceinline__ void gbar(unsigned* bcnt, unsigned* bgen, int tid)
{
    __threadfence();                           // release: flush L2 writes
    __syncthreads();
    if (tid == 0) {
        unsigned g = __hip_atomic_load(bgen, __ATOMIC_RELAXED, __HIP_MEMORY_SCOPE_AGENT);
        if (__hip_atomic_fetch_add(bcnt, 1u, __ATOMIC_ACQ_REL, __HIP_MEMORY_SCOPE_AGENT)
            == NB - 1u) {
            __hip_atomic_store(bcnt, 0u, __ATOMIC_RELAXED, __HIP_MEMORY_SCOPE_AGENT);
            __hip_atomic_store(bgen, g + 1u, __ATOMIC_RELEASE, __HIP_MEMORY_SCOPE_AGENT);
        } else {
            while (__hip_atomic_load(bgen, __ATOMIC_RELAXED, __HIP_MEMORY_SCOPE_AGENT) == g)
                __builtin_amdgcn_s_sleep(1);
        }
    }
    __syncthreads();
    __threadfence();                           // acquire: invalidate stale caches
}

// ---------------------------------------------------------------------------
static __device__ __forceinline__ void calc_scsh(const float* Sslot, float inv_denom,
    const float* __restrict__ g, const float* __restrict__ b, float* SCSH, int tid)
{
    if (tid < 64) {
        float s = 0.f, q = 0.f;
        #pragma unroll
        for (int sh = 0; sh < 4; ++sh) {
            s += Sslot[sh * 128 + tid];
            q += Sslot[sh * 128 + 64 + tid];
        }
        float m   = s * inv_denom;
        float var = q * inv_denom - m * m;
        float sc  = g[tid] * rsqrtf(var + BN_EPS);
        SCSH[tid] = sc; SCSH[64 + tid] = b[tid] - m * sc;
    }
}

static __device__ __forceinline__ void load_A_lds(const float* X, int band,
                                                  int l15, int kg, float xv[2][8])
{
    const float* p = X + (band + l15) * 68 + kg * 8;
    #pragma unroll
    for (int ks = 0; ks < 2; ++ks) {
        float4 a0 = *(const float4*)(p + ks * 32);
        float4 a1 = *(const float4*)(p + ks * 32 + 4);
        xv[ks][0]=a0.x; xv[ks][1]=a0.y; xv[ks][2]=a0.z; xv[ks][3]=a0.w;
        xv[ks][4]=a1.x; xv[ks][5]=a1.y; xv[ks][6]=a1.z; xv[ks][7]=a1.w;
    }
}

static __device__ __forceinline__ void load_A_glob(const float* src, int grow,
                                                   int l15, int kg, float xv[2][8])
{
    const float* p = src + (size_t)(grow + l15) * 64 + kg * 8;
    #pragma unroll
    for (int ks = 0; ks < 2; ++ks) {
        float4 a0 = *(const float4*)(p + ks * 32);
        float4 a1 = *(const float4*)(p + ks * 32 + 4);
        xv[ks][0]=a0.x; xv[ks][1]=a0.y; xv[ks][2]=a0.z; xv[ks][3]=a0.w;
        xv[ks][4]=a1.x; xv[ks][5]=a1.y; xv[ks][6]=a1.z; xv[ks][7]=a1.w;
    }
}

static __device__ __forceinline__ void pre_apply(float xv[2][8], const float* SCSH, int kg)
{
    #pragma unroll
    for (int ks = 0; ks < 2; ++ks)
        #pragma unroll
        for (int j = 0; j < 8; ++j) {
            int k = ks * 32 + kg * 8 + j;
            xv[ks][j] = fmaxf(xv[ks][j] * SCSH[k] + SCSH[64 + k], 0.f);
        }
}

static __device__ __forceinline__ void mfma3(const float xv[2][8],
    const unsigned short* __restrict__ whi, const unsigned short* __restrict__ wlo,
    const float* __restrict__ bias, int l15, int kg, f32x4 d[4])
{
    bf16x8 ahi[2], alo[2];
    #pragma unroll
    for (int ks = 0; ks < 2; ++ks) {
        bf16x8 th, tl;
        #pragma unroll
        for (int j = 0; j < 8; ++j) {
            unsigned short h = f2bf(xv[ks][j]);
            th[j] = (short)h;
            tl[j] = (short)f2bf(xv[ks][j] - bf2f(h));
        }
        ahi[ks] = th; alo[ks] = tl;
    }
    #pragma unroll
    for (int ct = 0; ct < 4; ++ct) {
        float bc = bias ? bias[ct * 16 + l15] : 0.f;
        d[ct] = (f32x4){bc, bc, bc, bc};
    }
    #pragma unroll
    for (int ct = 0; ct < 4; ++ct) {
        const unsigned short* hrow = whi + (ct * 16 + l15) * 64 + kg * 8;
        const unsigned short* lrow = wlo + (ct * 16 + l15) * 64 + kg * 8;
        #pragma unroll
        for (int ks = 0; ks < 2; ++ks) {
            bf16x8 wh = *(const bf16x8*)(hrow + ks * 32);
            bf16x8 wl = *(const bf16x8*)(lrow + ks * 32);
            d[ct] = __builtin_amdgcn_mfma_f32_16x16x32_bf16(ahi[ks], wh, d[ct], 0, 0, 0);
            d[ct] = __builtin_amdgcn_mfma_f32_16x16x32_bf16(alo[ks], wh, d[ct], 0, 0, 0);
            d[ct] = __builtin_amdgcn_mfma_f32_16x16x32_bf16(ahi[ks], wl, d[ct], 0, 0, 0);
        }
    }
}

static __device__ __forceinline__ void store_D_lds(float* X, int band,
                                                   const f32x4 d[4], int l15, int kg)
{
    #pragma unroll
    for (int ct = 0; ct < 4; ++ct)
        #pragma unroll
        for (int i = 0; i < 4; ++i)
            X[(band + kg * 4 + i) * 68 + ct * 16 + l15] = d[ct][i];
}

static __device__ __forceinline__ void store_D_glob(float* g, int grow,
                                                    const f32x4 d[4], int l15, int kg)
{
    #pragma unroll
    for (int ct = 0; ct < 4; ++ct)
        #pragma unroll
        for (int i = 0; i < 4; ++i)
            g[(size_t)(grow + kg * 4 + i) * 64 + ct * 16 + l15] = d[ct][i];
}

static __device__ __forceinline__ void stats_D(const f32x4 d[4], const unsigned* cw,
    float* Sdst, float (*LS)[64], float (*LQ)[64], int tid, int wid, int l15, int kg)
{
    float w[4] = {1.f, 1.f, 1.f, 1.f};
    if (cw) {
        #pragma unroll
        for (int i = 0; i < 4; ++i) w[i] = (float)cw[kg * 4 + i];
    }
    #pragma unroll
    for (int ct = 0; ct < 4; ++ct) {
        float t = 0.f, t2 = 0.f;
        #pragma unroll
        for (int i = 0; i < 4; ++i) {
            float v = d[ct][i];
            t += w[i] * v; t2 += w[i] * v * v;
        }
        t  += __shfl_xor(t, 16);  t  += __shfl_xor(t, 32);
        t2 += __shfl_xor(t2, 16); t2 += __shfl_xor(t2, 32);
        if (kg == 0) { LS[wid][ct * 16 + l15] = t; LQ[wid][ct * 16 + l15] = t2; }
    }
    __syncthreads();
    if (tid < 64)        atomicAdd(Sdst + tid,      LS[0][tid]+LS[1][tid]+LS[2][tid]+LS[3][tid]);
    else if (tid < 128) { int c = tid - 64;
                          atomicAdd(Sdst + 64 + c,  LQ[0][c]+LQ[1][c]+LQ[2][c]+LQ[3][c]); }
    __syncthreads();
}

// ---------------------------------------------------------------------------
__global__ __launch_bounds__(256, 2) void fused_kernel(FParams P)
{
    __shared__ float X[RPB * 68];            // 34816 B transpose/xm staging
    __shared__ float SCSH[128];
    __shared__ float LS[4][64], LQ[4][64];

    const int tid  = threadIdx.x;
    const int lane = tid & 63, wid = tid >> 6;
    const int l15  = lane & 15, kg = lane >> 4;
    const int row0 = blockIdx.x * RPB;
    const int bsel = blockIdx.x & 3;
    const float invN  = 1.f / (float)N_PTS;
    const float invNK = invN / 16.f;
    unsigned* bcnt = P.bar;
    unsigned* bgen = P.bar + 32;

    // histogram of this block's ref rows (consumed after barrier 1)
    {
        const int4* rp = (const int4*)(P.ref + row0 * 16) + tid * 2;
        int4 a = rp[0], b = rp[1];
        atomicAdd(&P.cnt[a.x], 1u); atomicAdd(&P.cnt[a.y], 1u);
        atomicAdd(&P.cnt[a.z], 1u); atomicAdd(&P.cnt[a.w], 1u);
        atomicAdd(&P.cnt[b.x], 1u); atomicAdd(&P.cnt[b.y], 1u);
        atomicAdd(&P.cnt[b.z], 1u); atomicAdd(&P.cnt[b.w], 1u);
    }

    float xv[2][8];
    f32x4 d[4];

    #pragma unroll 1
    for (int db = 0; db < 2; ++db) {
        const int po = db * 64;
        float* Sb = P.Sb + db * 5 * 512;
        const unsigned short* W0h = P.Whi + (0*2+db)*4096, *W0l = P.Wlo + (0*2+db)*4096;
        const unsigned short* W1h = P.Whi + (1*2+db)*4096, *W1l = P.Wlo + (1*2+db)*4096;
        const unsigned short* W2h = P.Whi + (2*2+db)*4096, *W2l = P.Wlo + (2*2+db)*4096;
        const unsigned short* W3h = P.Whi + (3*2+db)*4096, *W3l = P.Wlo + (3*2+db)*4096;

        // ---- S_A: y1 = act @ fc1^T -> X ; bn1 stats ----
        {
            const float* asrc = db ? P.out : P.feat;
            #pragma unroll
            for (int h = 0; h < 2; ++h) {
                const int band = h * 64 + wid * 16;
                load_A_glob(asrc, row0 + band, l15, kg, xv);
                mfma3(xv, W0h, W0l, nullptr, l15, kg, d);
                store_D_lds(X, band, d, l15, kg);
                stats_D(d, nullptr, Sb + 0*512 + bsel*128, LS, LQ, tid, wid, l15, kg);
            }
        }
        gbar(bcnt, bgen, tid);

        // ---- S_B: y2 = relu(bn1(y1)) @ la_w1^T + b1 -> X ; wtd stats ----
        calc_scsh(Sb + 0*512, invN, P.bn1_g + po, P.bn1_b + po, SCSH, tid);
        __syncthreads();
        #pragma unroll
        for (int h = 0; h < 2; ++h) {
            const int band = h * 64 + wid * 16;
            load_A_lds(X, band, l15, kg, xv);
            pre_apply(xv, SCSH, kg);
            mfma3(xv, W1h, W1l, P.la_b1 + po, l15, kg, d);
            store_D_lds(X, band, d, l15, kg);
            stats_D(d, P.cnt + row0 + band, Sb + 1*512 + bsel*128, LS, LQ, tid, wid, l15, kg);
        }
        gbar(bcnt, bgen, tid);

        // ---- S_C: y3 = relu(bnA(y2)) @ la_w2^T + b2 -> global ; wtd stats ----
        calc_scsh(Sb + 1*512, invNK, P.la_bn1g + po, P.la_bn1b + po, SCSH, tid);
        __syncthreads();
        #pragma unroll
        for (int h = 0; h < 2; ++h) {
            const int band = h * 64 + wid * 16;
            load_A_lds(X, band, l15, kg, xv);
            pre_apply(xv, SCSH, kg);
            mfma3(xv, W2h, W2l, P.la_b2 + po, l15, kg, d);
            store_D_glob(P.y3, row0 + band, d, l15, kg);
            stats_D(d, P.cnt + row0 + band, Sb + 2*512 + bsel*128, LS, LQ, tid, wid, l15, kg);
        }
        gbar(bcnt, bgen, tid);

        // ---- S_E: xm = relu(bnB(max_k y3[ref])) -> X ; stats (monotone bn) ----
        calc_scsh(Sb + 2*512, invNK, P.la_bn2g + po, P.la_bn2b + po, SCSH, tid);
        __syncthreads();
        {
            const int rr = lane >> 4, c4 = lane & 15;
            const float sc0 = SCSH[c4*4+0], sc1 = SCSH[c4*4+1],
                        sc2 = SCSH[c4*4+2], sc3 = SCSH[c4*4+3];
            const float sh0 = SCSH[64+c4*4+0], sh1 = SCSH[64+c4*4+1],
                        sh2 = SCSH[64+c4*4+2], sh3 = SCSH[64+c4*4+3];
            float s0=0.f,s1=0.f,s2=0.f,s3=0.f, q0=0.f,q1=0.f,q2=0.f,q3=0.f;
            #pragma unroll
            for (int g = 0; g < 8; ++g) {
                const int rloc = wid * 32 + g * 4 + rr;
                int jv = P.ref[(row0 + rloc) * 16 + c4];
                float4 v[16];
                #pragma unroll
                for (int t = 0; t < 16; ++t) {
                    int j = __shfl(jv, rr * 16 + t);
                    v[t] = *(const float4*)(P.y3 + (size_t)j * 64 + c4 * 4);
                }
                float4 mx = v[0];
                #pragma unroll
                for (int t = 1; t < 16; ++t) {
                    mx.x = fmaxf(mx.x, v[t].x); mx.y = fmaxf(mx.y, v[t].y);
                    mx.z = fmaxf(mx.z, v[t].z); mx.w = fmaxf(mx.w, v[t].w);
                }
                float x0 = fmaxf(mx.x * sc0 + sh0, 0.f);
                float x1 = fmaxf(mx.y * sc1 + sh1, 0.f);
                float x2 = fmaxf(mx.z * sc2 + sh2, 0.f);
                float x3 = fmaxf(mx.w * sc3 + sh3, 0.f);
                *(float4*)(X + rloc * 68 + c4 * 4) = make_float4(x0, x1, x2, x3);
                s0 += x0; q0 += x0*x0; s1 += x1; q1 += x1*x1;
                s2 += x2; q2 += x2*x2; s3 += x3; q3 += x3*x3;
            }
            s0 += __shfl_xor(s0,16); s0 += __shfl_xor(s0,32);
            s1 += __shfl_xor(s1,16); s1 += __shfl_xor(s1,32);
            s2 += __shfl_xor(s2,16); s2 += __shfl_xor(s2,32);
            s3 += __shfl_xor(s3,16); s3 += __shfl_xor(s3,32);
            q0 += __shfl_xor(q0,16); q0 += __shfl_xor(q0,32);
            q1 += __shfl_xor(q1,16); q1 += __shfl_xor(q1,32);
            q2 += __shfl_xor(q2,16); q2 += __shfl_xor(q2,32);
            q3 += __shfl_xor(q3,16); q3 += __shfl_xor(q3,32);
            if (rr == 0) {
                LS[wid][c4*4+0]=s0; LS[wid][c4*4+1]=s1; LS[wid][c4*4+2]=s2; LS[wid][c4*4+3]=s3;
                LQ[wid][c4*4+0]=q0; LQ[wid][c4*4+1]=q1; LQ[wid][c4*4+2]=q2; LQ[wid][c4*4+3]=q3;
            }
            __syncthreads();
            float* Sdst = Sb + 3*512 + bsel*128;
            if (tid < 64)        atomicAdd(Sdst + tid,     LS[0][tid]+LS[1][tid]+LS[2][tid]+LS[3][tid]);
            else if (tid < 128) { int c = tid - 64;
                                  atomicAdd(Sdst + 64 + c, LQ[0][c]+LQ[1][c]+LQ[2][c]+LQ[3][c]); }
        }
        gbar(bcnt, bgen, tid);

        // ---- S_F: y4 = relu(bn2(xm)) @ fc3^T -> X ; bn3 stats ----
        calc_scsh(Sb + 3*512, invN, P.bn2_g + po, P.bn2_b + po, SCSH, tid);
        __syncthreads();
        #pragma unroll
        for (int h = 0; h < 2; ++h) {
            const int band = h * 64 + wid * 16;
            load_A_lds(X, band, l15, kg, xv);
            pre_apply(xv, SCSH, kg);
            mfma3(xv, W3h, W3l, nullptr, l15, kg, d);
            store_D_lds(X, band, d, l15, kg);
            stats_D(d, nullptr, Sb + 4*512 + bsel*128, LS, LQ, tid, wid, l15, kg);
        }
        gbar(bcnt, bgen, tid);

        // ---- S_G: act' = relu(identity + bn3(y4)) ----
        calc_scsh(Sb + 4*512, invN, P.bn3_g + po, P.bn3_b + po, SCSH, tid);
        __syncthreads();
        #pragma unroll
        for (int h = 0; h < 2; ++h) {
            const int band = h * 64 + wid * 16;
            const int grow = row0 + band;
            #pragma unroll
            for (int ct = 0; ct < 4; ++ct)
                #pragma unroll
                for (int i = 0; i < 4; ++i) {
                    const int c = ct * 16 + l15;
                    const int r = kg * 4 + i;
                    float y4v = X[(band + r) * 68 + c];
                    float idv = (db == 0)
                        ? P.feat[(size_t)(grow + r) * 64 + c]
                        : P.out [(size_t)(grow + r) * 64 + c];
                    P.out[(size_t)(grow + r) * 64 + c] =
                        fmaxf(idv + y4v * SCSH[c] + SCSH[64 + c], 0.f);
                }
        }
        // no grid barrier needed: db=1 S_A reads only this block's own rows
    }
}

// ---------------------------------------------------------------------------
extern "C" void kernel_launch(void* const* d_in, const int* in_sizes, int n_in,
                              void* d_out, int out_size, void* d_ws, size_t ws_size,
                              hipStream_t stream)
{
    const float* feat    = (const float*)d_in[1];
    const int*   ref     = (const int*)  d_in[2];
    const float* fc1_w   = (const float*)d_in[3];
    const float* bn1_g   = (const float*)d_in[4];
    const float* bn1_b   = (const float*)d_in[5];
    const float* la_w1   = (const float*)d_in[6];
    const float* la_b1   = (const float*)d_in[7];
    const float* la_bn1g = (const float*)d_in[8];
    const float* la_bn1b = (const float*)d_in[9];
    const float* la_w2   = (const float*)d_in[10];
    const float* la_b2   = (const float*)d_in[11];
    const float* la_bn2g = (const float*)d_in[12];
    const float* la_bn2b = (const float*)d_in[13];
    const float* fc3_w   = (const float*)d_in[14];
    const float* bn2_g   = (const float*)d_in[15];
    const float* bn2_b   = (const float*)d_in[16];
    const float* bn3_g   = (const float*)d_in[17];
    const float* bn3_b   = (const float*)d_in[18];
    float* out = (float*)d_out;

    // ws: y3 16MB | cnt 256KB | Sb 20KB | bar 256B | Whi 64KB | Wlo 64KB
    char* base = (char*)d_ws;
    float*    y3  = (float*)base;
    unsigned* cnt = (unsigned*)(base + 16u * 1024 * 1024);
    float*    Sb  = (float*)(cnt + N_PTS);
    unsigned* bar = (unsigned*)(Sb + 10 * 512);
    unsigned short* Whi = (unsigned short*)(bar + 64);
    unsigned short* Wlo = Whi + 8 * 4096;

    hipMemsetAsync(cnt, 0,
        N_PTS * sizeof(unsigned) + 10 * 512 * sizeof(float) + 64 * sizeof(unsigned),
        stream);
    wconv_kernel<<<128, 256, 0, stream>>>(fc1_w, la_w1, la_w2, fc3_w, Whi, Wlo);

    FParams p;
    p.feat = feat; p.ref = ref; p.Whi = Whi; p.Wlo = Wlo;
    p.la_b1 = la_b1; p.la_b2 = la_b2;
    p.bn1_g = bn1_g; p.bn1_b = bn1_b;
    p.la_bn1g = la_bn1g; p.la_bn1b = la_bn1b;
    p.la_bn2g = la_bn2g; p.la_bn2b = la_bn2b;
    p.bn2_g = bn2_g; p.bn2_b = bn2_b;
    p.bn3_g = bn3_g; p.bn3_b = bn3_b;
    p.cnt = cnt; p.Sb = Sb; p.bar = bar; p.y3 = y3; p.out = out;

    fused_kernel<<<NB, 256, 0, stream>>>(p);
}

// Round 6
// 241.962 us; speedup vs baseline: 4.0497x; 4.0497x over previous
//
#include <hip/hip_runtime.h>

#define N_PTS 65536
#define BN_EPS 1e-5f

typedef __attribute__((ext_vector_type(8))) short bf16x8;
typedef __attribute__((ext_vector_type(4))) float f32x4;

static __device__ __forceinline__ unsigned short f2bf(float f) {
    unsigned u = __builtin_bit_cast(unsigned, f);
    u += 0x7fffu + ((u >> 16) & 1u);          // round-to-nearest-even
    return (unsigned short)(u >> 16);
}
static __device__ __forceinline__ float bf2f(unsigned short h) {
    unsigned u = ((unsigned)h) << 16;
    return __builtin_bit_cast(float, u);
}
static __device__ __forceinline__ unsigned pack2(float a, float b) {
    return (unsigned)f2bf(a) | ((unsigned)f2bf(b) << 16);
}

// ---------------------------------------------------------------------------
// split 8 weight matrices into bf16 hi/lo; slot = kind*2 + d, 4096 elems each
__global__ __launch_bounds__(256) void wconv_kernel(
    const float* __restrict__ fc1, const float* __restrict__ la1,
    const float* __restrict__ la2, const float* __restrict__ fc3,
    unsigned short* __restrict__ hi, unsigned short* __restrict__ lo)
{
    int i = blockIdx.x * 256 + threadIdx.x;   // 0..32767
    const float* p = (i < 8192) ? fc1 : (i < 16384) ? la1
                   : (i < 24576) ? la2 : fc3;
    float w = p[i & 8191];
    unsigned short h = f2bf(w);
    hi[i] = h;
    lo[i] = f2bf(w - bf2f(h));
}

// ---------------------------------------------------------------------------
// Fused (pre-op) -> 64x64 matmul (bf16x3 MFMA, ~fp32 accuracy) -> stats.
// PRE: 0 none; 1 x=relu(x*sc+sh); 2 x=relu(identity + x*sc+sh), write x->f1_out
// OUTBF: pack output to bf16 pairs (via LDS transpose). HIST: histogram ref.
// wave = 16-row m-tile; block = 4 waves = 64 rows; grid = 1024.
template<int PRE, int BIAS, int WTD, int OUTBF, int HIST>
__global__ __launch_bounds__(256) void mm_kernel(
    const float* __restrict__ in,    const float* __restrict__ identity,
    const unsigned short* __restrict__ whi, const unsigned short* __restrict__ wlo,
    const float* __restrict__ bias,
    const float* __restrict__ gg,    const float* __restrict__ bb,
    const float* __restrict__ S_in,  float inv_denom,
    void*        __restrict__ outv,  float* __restrict__ S_out,
    const unsigned* __restrict__ cw, float* __restrict__ f1_out,
    const int* __restrict__ ref,     unsigned* __restrict__ hdst)
{
    __shared__ float sc[64], sh[64];
    __shared__ float lsum[4][64], lss[4][64];
    const int tid  = threadIdx.x;
    const int lane = tid & 63, wid = tid >> 6;
    const int l15  = lane & 15, kg = lane >> 4;
    const int brow = blockIdx.x * 64;
    const int arow = brow + wid * 16 + l15;

    // ---- early global loads: issue before the BN prologue ----
    const float4* ap = (const float4*)(in + (size_t)arow * 64 + kg * 8);
    float4 a0 = ap[0], a1 = ap[1], a2 = ap[8], a3 = ap[9];
    float4 i0, i1, i2, i3;
    if (PRE == 2) {
        const float4* ip = (const float4*)(identity + (size_t)arow * 64 + kg * 8);
        i0 = ip[0]; i1 = ip[1]; i2 = ip[8]; i3 = ip[9];
    }
    float wt[4] = {1.f, 1.f, 1.f, 1.f};
    if (WTD) {
        #pragma unroll
        for (int i = 0; i < 4; ++i)
            wt[i] = (float)cw[brow + wid * 16 + kg * 4 + i];
    }
    if (HIST) {
        int4 hv = ((const int4*)(ref + brow * 16))[tid];
        atomicAdd(&hdst[hv.x], 1u); atomicAdd(&hdst[hv.y], 1u);
        atomicAdd(&hdst[hv.z], 1u); atomicAdd(&hdst[hv.w], 1u);
    }

    // ---- BN prologue: fold stats into scale/shift ----
    if (PRE >= 1) {
        if (tid < 64) {
            float s = 0.f, q = 0.f;
            #pragma unroll
            for (int g = 0; g < 8; ++g) {
                s += S_in[g * 128 + tid];
                q += S_in[g * 128 + 64 + tid];
            }
            float m   = s * inv_denom;
            float var = q * inv_denom - m * m;
            float scl = gg[tid] * rsqrtf(var + BN_EPS);
            sc[tid] = scl; sh[tid] = bb[tid] - m * scl;
        }
        __syncthreads();
    }

    float xv[2][8];
    xv[0][0]=a0.x; xv[0][1]=a0.y; xv[0][2]=a0.z; xv[0][3]=a0.w;
    xv[0][4]=a1.x; xv[0][5]=a1.y; xv[0][6]=a1.z; xv[0][7]=a1.w;
    xv[1][0]=a2.x; xv[1][1]=a2.y; xv[1][2]=a2.z; xv[1][3]=a2.w;
    xv[1][4]=a3.x; xv[1][5]=a3.y; xv[1][6]=a3.z; xv[1][7]=a3.w;

    if (PRE == 1) {
        #pragma unroll
        for (int ks = 0; ks < 2; ++ks)
            #pragma unroll
            for (int j = 0; j < 8; ++j) {
                int k = ks * 32 + kg * 8 + j;
                xv[ks][j] = fmaxf(xv[ks][j] * sc[k] + sh[k], 0.f);
            }
    } else if (PRE == 2) {
        float idv[2][8];
        idv[0][0]=i0.x; idv[0][1]=i0.y; idv[0][2]=i0.z; idv[0][3]=i0.w;
        idv[0][4]=i1.x; idv[0][5]=i1.y; idv[0][6]=i1.z; idv[0][7]=i1.w;
        idv[1][0]=i2.x; idv[1][1]=i2.y; idv[1][2]=i2.z; idv[1][3]=i2.w;
        idv[1][4]=i3.x; idv[1][5]=i3.y; idv[1][6]=i3.z; idv[1][7]=i3.w;
        #pragma unroll
        for (int ks = 0; ks < 2; ++ks) {
            #pragma unroll
            for (int j = 0; j < 8; ++j) {
                int k = ks * 32 + kg * 8 + j;
                xv[ks][j] = fmaxf(idv[ks][j] + xv[ks][j] * sc[k] + sh[k], 0.f);
            }
            float* f1p = f1_out + (size_t)arow * 64 + kg * 8 + ks * 32;
            *(float4*)(f1p)     = make_float4(xv[ks][0], xv[ks][1], xv[ks][2], xv[ks][3]);
            *(float4*)(f1p + 4) = make_float4(xv[ks][4], xv[ks][5], xv[ks][6], xv[ks][7]);
        }
    }

    // ---- split A into hi+lo bf16; MFMA D = Ahi@Whi + Alo@Whi + Ahi@Wlo ----
    bf16x8 ahi[2], alo[2];
    #pragma unroll
    for (int ks = 0; ks < 2; ++ks) {
        bf16x8 th, tl;
        #pragma unroll
        for (int j = 0; j < 8; ++j) {
            unsigned short h = f2bf(xv[ks][j]);
            th[j] = (short)h;
            tl[j] = (short)f2bf(xv[ks][j] - bf2f(h));
        }
        ahi[ks] = th; alo[ks] = tl;
    }
    f32x4 d[4];
    #pragma unroll
    for (int ct = 0; ct < 4; ++ct) {
        float bc = BIAS ? bias[ct * 16 + l15] : 0.f;
        d[ct] = (f32x4){bc, bc, bc, bc};
    }
    #pragma unroll
    for (int ct = 0; ct < 4; ++ct) {
        const unsigned short* hrow = whi + (ct * 16 + l15) * 64 + kg * 8;
        const unsigned short* lrow = wlo + (ct * 16 + l15) * 64 + kg * 8;
        #pragma unroll
        for (int ks = 0; ks < 2; ++ks) {
            bf16x8 wh = *(const bf16x8*)(hrow + ks * 32);
            bf16x8 wl = *(const bf16x8*)(lrow + ks * 32);
            d[ct] = __builtin_amdgcn_mfma_f32_16x16x32_bf16(ahi[ks], wh, d[ct], 0, 0, 0);
            d[ct] = __builtin_amdgcn_mfma_f32_16x16x32_bf16(alo[ks], wh, d[ct], 0, 0, 0);
            d[ct] = __builtin_amdgcn_mfma_f32_16x16x32_bf16(ahi[ks], wl, d[ct], 0, 0, 0);
        }
    }

    // ---- stats: D row = kg*4+i, col = ct*16+l15 ----
    #pragma unroll
    for (int ct = 0; ct < 4; ++ct) {
        float t = 0.f, t2 = 0.f;
        #pragma unroll
        for (int i = 0; i < 4; ++i) {
            float v = d[ct][i];
            t += wt[i] * v; t2 += wt[i] * v * v;
        }
        t  += __shfl_xor(t, 16);  t  += __shfl_xor(t, 32);
        t2 += __shfl_xor(t2, 16); t2 += __shfl_xor(t2, 32);
        if (kg == 0) { lsum[wid][ct * 16 + l15] = t; lss[wid][ct * 16 + l15] = t2; }
    }
    __syncthreads();
    const int bsel = blockIdx.x & 7;
    if (tid < 64)
        atomicAdd(S_out + bsel * 128 + tid,
                  lsum[0][tid]+lsum[1][tid]+lsum[2][tid]+lsum[3][tid]);
    else if (tid < 128) {
        int c = tid - 64;
        atomicAdd(S_out + bsel * 128 + 64 + c,
                  lss[0][c]+lss[1][c]+lss[2][c]+lss[3][c]);
    }

    // ---- store ----
    if (!OUTBF) {
        float* op = (float*)outv;
        #pragma unroll
        for (int ct = 0; ct < 4; ++ct)
            #pragma unroll
            for (int i = 0; i < 4; ++i)
                op[(size_t)(brow + wid * 16 + kg * 4 + i) * 64 + ct * 16 + l15] = d[ct][i];
    } else {
        __shared__ float stg[4][16][65];
        #pragma unroll
        for (int ct = 0; ct < 4; ++ct)
            #pragma unroll
            for (int i = 0; i < 4; ++i)
                stg[wid][kg * 4 + i][ct * 16 + l15] = d[ct][i];
        __syncthreads();
        const float* srow = &stg[wid][l15][kg * 16];
        unsigned pk[8];
        #pragma unroll
        for (int q = 0; q < 8; ++q) pk[q] = pack2(srow[2 * q], srow[2 * q + 1]);
        unsigned* op = (unsigned*)outv;
        uint4* dst = (uint4*)(op + (size_t)(brow + wid * 16 + l15) * 32 + kg * 8);
        dst[0] = make_uint4(pk[0], pk[1], pk[2], pk[3]);
        dst[1] = make_uint4(pk[4], pk[5], pk[6], pk[7]);
    }
}

// ---------------------------------------------------------------------------
// xm[r,c] = relu(bn(max_k y3[ref[r,k],c])), y3 bf16-packed (u32 = 2 channels).
// half-wave = one row (lane = channel pair); xm fp32; inline stats over N.
__global__ __launch_bounds__(256) void gather_kernel(
    const unsigned* __restrict__ y3u, const int* __restrict__ ref,
    const float* __restrict__ S_in, float inv_denom,
    const float* __restrict__ gg, const float* __restrict__ bb,
    float* __restrict__ xm, float* __restrict__ S_out)
{
    __shared__ float scs[64], shs[64], Rs[256], Rq[256];
    const int tid = threadIdx.x;
    if (tid < 64) {
        float s = 0.f, q = 0.f;
        #pragma unroll
        for (int g = 0; g < 8; ++g) {
            s += S_in[g * 128 + tid];
            q += S_in[g * 128 + 64 + tid];
        }
        float m   = s * inv_denom;
        float var = q * inv_denom - m * m;
        float scl = gg[tid] * rsqrtf(var + BN_EPS);
        scs[tid] = scl; shs[tid] = bb[tid] - m * scl;
    }
    __syncthreads();
    const int lane = tid & 63, wid = tid >> 6;
    const int c2 = lane & 31;
    const int hsel = lane & 32;                 // 0 or 32 -> even/odd row
    const float sc0 = scs[2*c2], sc1 = scs[2*c2+1];
    const float sh0 = shs[2*c2], sh1 = shs[2*c2+1];
    float s0=0.f, q0=0.f, s1=0.f, q1=0.f;
    for (int p = blockIdx.x * 4 + wid; p < N_PTS / 2; p += 2048 * 4) {
        const int r = 2 * p + (hsel ? 1 : 0);
        int jv = ref[r * 16 + (lane & 15)];     // preload row's 16 indices
        unsigned u[16];
        #pragma unroll
        for (int t = 0; t < 16; ++t) {
            int j = __shfl(jv, hsel + t);
            u[t] = y3u[(size_t)j * 32 + c2];
        }
        float m0 = bf2f((unsigned short)(u[0] & 0xffffu));
        float m1 = bf2f((unsigned short)(u[0] >> 16));
        #pragma unroll
        for (int t = 1; t < 16; ++t) {
            m0 = fmaxf(m0, bf2f((unsigned short)(u[t] & 0xffffu)));
            m1 = fmaxf(m1, bf2f((unsigned short)(u[t] >> 16)));
        }
        float x0 = fmaxf(m0 * sc0 + sh0, 0.f);  // bn monotone (gamma=1>0)
        float x1 = fmaxf(m1 * sc1 + sh1, 0.f);
        *(float2*)(xm + (size_t)r * 64 + 2 * c2) = make_float2(x0, x1);
        s0 += x0; q0 += x0 * x0; s1 += x1; q1 += x1 * x1;
    }
    const int bsel = blockIdx.x & 7;
    Rs[tid] = s0; Rq[tid] = q0;
    __syncthreads();
    if (tid < 32) {
        float a = 0.f, c = 0.f;
        #pragma unroll
        for (int i = 0; i < 8; ++i) { a += Rs[tid + 32*i]; c += Rq[tid + 32*i]; }
        atomicAdd(S_out + bsel*128 + 2*tid, a);
        atomicAdd(S_out + bsel*128 + 64 + 2*tid, c);
    }
    __syncthreads();
    Rs[tid] = s1; Rq[tid] = q1;
    __syncthreads();
    if (tid < 32) {
        float a = 0.f, c = 0.f;
        #pragma unroll
        for (int i = 0; i < 8; ++i) { a += Rs[tid + 32*i]; c += Rq[tid + 32*i]; }
        atomicAdd(S_out + bsel*128 + 2*tid + 1, a);
        atomicAdd(S_out + bsel*128 + 64 + 2*tid + 1, c);
    }
}

// ---------------------------------------------------------------------------
// io = relu(io + y4*sc + sh)   (final residual, in place)
__global__ __launch_bounds__(256) void res_final(
    float* __restrict__ io, const float* __restrict__ y4,
    const float* __restrict__ S_in, float inv_denom,
    const float* __restrict__ gg, const float* __restrict__ bb)
{
    __shared__ float sc[64], sh[64];
    const int tid = threadIdx.x;
    int i = blockIdx.x * 256 + tid;            // float4 index
    float4 idv = ((const float4*)io)[i];
    float4 yv  = ((const float4*)y4)[i];
    if (tid < 64) {
        float s = 0.f, q = 0.f;
        #pragma unroll
        for (int g = 0; g < 8; ++g) {
            s += S_in[g * 128 + tid];
            q += S_in[g * 128 + 64 + tid];
        }
        float m   = s * inv_denom;
        float var = q * inv_denom - m * m;
        float scl = gg[tid] * rsqrtf(var + BN_EPS);
        sc[tid] = scl; sh[tid] = bb[tid] - m * scl;
    }
    __syncthreads();
    int c0 = (i * 4) & 63;
    float4 o;
    o.x = fmaxf(idv.x + yv.x * sc[c0+0] + sh[c0+0], 0.f);
    o.y = fmaxf(idv.y + yv.y * sc[c0+1] + sh[c0+1], 0.f);
    o.z = fmaxf(idv.z + yv.z * sc[c0+2] + sh[c0+2], 0.f);
    o.w = fmaxf(idv.w + yv.w * sc[c0+3] + sh[c0+3], 0.f);
    ((float4*)io)[i] = o;
}

// ---------------------------------------------------------------------------
extern "C" void kernel_launch(void* const* d_in, const int* in_sizes, int n_in,
                              void* d_out, int out_size, void* d_ws, size_t ws_size,
                              hipStream_t stream)
{
    const float* feat    = (const float*)d_in[1];
    const int*   ref     = (const int*)  d_in[2];
    const float* fc1_w   = (const float*)d_in[3];
    const float* bn1_g   = (const float*)d_in[4];
    const float* bn1_b   = (const float*)d_in[5];
    const float* la_w1   = (const float*)d_in[6];
    const float* la_b1   = (const float*)d_in[7];
    const float* la_bn1g = (const float*)d_in[8];
    const float* la_bn1b = (const float*)d_in[9];
    const float* la_w2   = (const float*)d_in[10];
    const float* la_b2   = (const float*)d_in[11];
    const float* la_bn2g = (const float*)d_in[12];
    const float* la_bn2b = (const float*)d_in[13];
    const float* fc3_w   = (const float*)d_in[14];
    const float* bn2_g   = (const float*)d_in[15];
    const float* bn2_b   = (const float*)d_in[16];
    const float* bn3_g   = (const float*)d_in[17];
    const float* bn3_b   = (const float*)d_in[18];
    float* out = (float*)d_out;

    // ws: R1 16MB | R2 16MB | cnt 256KB | Sb 40KB | Whi 64KB | Wlo 64KB
    // y3 (bf16, 8MB) aliases the dead half-cycle buffer: d0 -> R1, d1 -> R2.
    char* base = (char*)d_ws;
    float*    R1  = (float*)base;
    float*    R2  = (float*)(base + 16u * 1024 * 1024);
    unsigned* cnt = (unsigned*)(base + 32u * 1024 * 1024);
    float*    Sb  = (float*)(cnt + N_PTS);
    unsigned short* Whi = (unsigned short*)(Sb + 10 * 1024);
    unsigned short* Wlo = Whi + 8 * 4096;
#define SS(i) (Sb + (i) * 1024)
#define WH(kind, d) (Whi + ((kind) * 2 + (d)) * 4096)
#define WL(kind, d) (Wlo + ((kind) * 2 + (d)) * 4096)

    hipMemsetAsync(cnt, 0, N_PTS * sizeof(unsigned) + 10 * 1024 * sizeof(float), stream);
    wconv_kernel<<<128, 256, 0, stream>>>(fc1_w, la_w1, la_w2, fc3_w, Whi, Wlo);

    const float invN  = 1.f / (float)N_PTS;
    const float invNK = invN / 16.f;
    const int MMG = N_PTS / 64;   // 1024 blocks

    // ---- block 0 ----
    mm_kernel<0,0,0,0,1><<<MMG,256,0,stream>>>(feat, nullptr, WH(0,0), WL(0,0),
        nullptr, nullptr, nullptr, nullptr, 0.f, R1, SS(0), nullptr, nullptr, ref, cnt);
    mm_kernel<1,1,1,0,0><<<MMG,256,0,stream>>>(R1, nullptr, WH(1,0), WL(1,0),
        la_b1, bn1_g, bn1_b, SS(0), invN, R2, SS(1), cnt, nullptr, nullptr, nullptr);
    mm_kernel<1,1,1,1,0><<<MMG,256,0,stream>>>(R2, nullptr, WH(2,0), WL(2,0),
        la_b2, la_bn1g, la_bn1b, SS(1), invNK, (void*)R1, SS(2), cnt, nullptr, nullptr, nullptr);
    gather_kernel<<<2048,256,0,stream>>>((const unsigned*)R1, ref, SS(2), invNK,
        la_bn2g, la_bn2b, R2, SS(3));
    mm_kernel<1,0,0,0,0><<<MMG,256,0,stream>>>(R2, nullptr, WH(3,0), WL(3,0),
        nullptr, bn2_g, bn2_b, SS(3), invN, R1, SS(4), nullptr, nullptr, nullptr, nullptr);

    // ---- block 1 (entry fuses block-0 residual; act0 -> out) ----
    mm_kernel<2,0,0,0,0><<<MMG,256,0,stream>>>(R1, feat, WH(0,1), WL(0,1),
        nullptr, bn3_g, bn3_b, SS(4), invN, R2, SS(5), nullptr, out, nullptr, nullptr);
    mm_kernel<1,1,1,0,0><<<MMG,256,0,stream>>>(R2, nullptr, WH(1,1), WL(1,1),
        la_b1 + 64, bn1_g + 64, bn1_b + 64, SS(5), invN, R1, SS(6), cnt, nullptr, nullptr, nullptr);
    mm_kernel<1,1,1,1,0><<<MMG,256,0,stream>>>(R1, nullptr, WH(2,1), WL(2,1),
        la_b2 + 64, la_bn1g + 64, la_bn1b + 64, SS(6), invNK, (void*)R2, SS(7), cnt, nullptr, nullptr, nullptr);
    gather_kernel<<<2048,256,0,stream>>>((const unsigned*)R2, ref, SS(7), invNK,
        la_bn2g + 64, la_bn2b + 64, R1, SS(8));
    mm_kernel<1,0,0,0,0><<<MMG,256,0,stream>>>(R1, nullptr, WH(3,1), WL(3,1),
        nullptr, bn2_g + 64, bn2_b + 64, SS(8), invN, R2, SS(9), nullptr, nullptr, nullptr, nullptr);
    res_final<<<(N_PTS * 64 / 4) / 256, 256, 0, stream>>>(out, R2, SS(9), invN,
        bn3_g + 64, bn3_b + 64);
}